// Round 2
// baseline (5954.198 us; speedup 1.0000x reference)
//
#include <hip/hip_runtime.h>

typedef unsigned int uint;
typedef unsigned short ushort;
typedef unsigned long long u64;
typedef short bf16x8 __attribute__((ext_vector_type(8)));
typedef float f32x4 __attribute__((ext_vector_type(4)));

#define DROP_VARIANT 2

// ---------------- workspace layout (bytes) ----------------
#define XW_OFF   0ull                        // ushort [2][64][1024][1024]  (dir,b,col,t) bf16
#define XB_OFF   (XW_OFF + 268435456ull)     // ushort [64*1024*256] x in bf16
#define WT_OFF   (XB_OFF + 33554432ull)      // ushort [2][1024][256]  W^T bf16
#define UT_OFF   (WT_OFF + 1048576ull)       // ushort [2][1024][256]  U^T bf16
#define HB_OFF   (UT_OFF + 1048576ull)       // ushort [2 par][2 dir][4 grp][2 half][16 b][128 u]
#define FL_OFF   (HB_OFF + 131072ull)        // uint flags[2 dir][4 grp][2 half][8 wave]
#define WS_NEED  (FL_OFF + 1024ull)

static __device__ __forceinline__ ushort f2bf(float f) {
  uint u = __float_as_uint(f);
  return (ushort)((u + 0x7fffu + ((u >> 16) & 1u)) >> 16);
}
static __device__ __forceinline__ float fsig(float x) {
  return 1.0f / (1.0f + __expf(-x));
}
static __device__ __forceinline__ float ftanh(float x) {
  return 1.0f - 2.0f / (__expf(2.0f * x) + 1.0f);
}
static __device__ __forceinline__ float bfsel(uint2 v, int p) {
  uint w = (p & 2) ? v.y : v.x;
  uint bits = (p & 1) ? (w & 0xffff0000u) : (w << 16);
  return __uint_as_float(bits);
}

// ================= convert: x->bf16, W^T, U^T =================
__global__ __launch_bounds__(256) void k_convert(
    const float* __restrict__ x,
    const float* __restrict__ Wf, const float* __restrict__ Wb,
    const float* __restrict__ Uf, const float* __restrict__ Ub,
    ushort* __restrict__ xb, ushort* __restrict__ wt, ushort* __restrict__ ut)
{
  uint tid = blockIdx.x * 256u + threadIdx.x;
  if (tid < 2097152u) {
    uint base = tid * 8u;
    float4 a = *(const float4*)(x + base);
    float4 b = *(const float4*)(x + base + 4);
    uint4 o;
    o.x = (uint)f2bf(a.x) | ((uint)f2bf(a.y) << 16);
    o.y = (uint)f2bf(a.z) | ((uint)f2bf(a.w) << 16);
    o.z = (uint)f2bf(b.x) | ((uint)f2bf(b.y) << 16);
    o.w = (uint)f2bf(b.z) | ((uint)f2bf(b.w) << 16);
    *(uint4*)(xb + base) = o;
  } else {
    uint e = tid - 2097152u;
    uint which = e >> 18;
    uint i = e & 262143u;
    uint n = i >> 8, k = i & 255u;
    const float* src = (which == 0) ? Wf : (which == 1) ? Wb : (which == 2) ? Uf : Ub;
    ushort v = f2bf(src[k * 1024u + n]);
    ushort* dst = (which < 2) ? (wt + which * 262144u) : (ut + (which - 2u) * 262144u);
    dst[n * 256u + k] = v;
  }
}

// ================= GEMM: xw[dir][b][col][t] = x @ W + bias =================
__global__ __launch_bounds__(256) void k_gemm(
    const ushort* __restrict__ xb, const ushort* __restrict__ wt,
    const float* __restrict__ biasF, const float* __restrict__ biasB,
    ushort* __restrict__ xw)
{
  const int dir = blockIdx.z;
  const ushort* W = wt + dir * 262144;
  const float* bias = dir ? biasB : biasF;
  const int m0 = blockIdx.x * 128;
  const int n0 = blockIdx.y * 128;
  const int tid = threadIdx.x;
  const int lane = tid & 63, wave = tid >> 6;
  const int l15 = lane & 15, l4 = lane >> 4;
  const int wr = wave >> 1, wc = wave & 1;

  __shared__ __align__(16) ushort lds[17408];
  ushort* As = lds;
  ushort* Bs = lds + 5120;

  f32x4 acc[4][4] = {};
  const int arow = tid >> 1, aseg = tid & 1;

  for (int kit = 0; kit < 8; ++kit) {
    int k0 = kit * 32;
    const ushort* sa = xb + (m0 + arow) * 256 + k0 + aseg * 16;
    uint4 a0 = *(const uint4*)sa;
    uint4 a1 = *(const uint4*)(sa + 8);
    const ushort* sb = W + (n0 + arow) * 256 + k0 + aseg * 16;
    uint4 b0 = *(const uint4*)sb;
    uint4 b1 = *(const uint4*)(sb + 8);
    *(uint4*)(As + arow * 40 + aseg * 16) = a0;
    *(uint4*)(As + arow * 40 + aseg * 16 + 8) = a1;
    *(uint4*)(Bs + arow * 40 + aseg * 16) = b0;
    *(uint4*)(Bs + arow * 40 + aseg * 16 + 8) = b1;
    __syncthreads();
    bf16x8 af[4], bfr[4];
#pragma unroll
    for (int m = 0; m < 4; ++m) af[m] = *(const bf16x8*)(As + (wr * 64 + m * 16 + l15) * 40 + l4 * 8);
#pragma unroll
    for (int n = 0; n < 4; ++n) bfr[n] = *(const bf16x8*)(Bs + (wc * 64 + n * 16 + l15) * 40 + l4 * 8);
#pragma unroll
    for (int m = 0; m < 4; ++m)
#pragma unroll
      for (int n = 0; n < 4; ++n)
        acc[m][n] = __builtin_amdgcn_mfma_f32_16x16x32_bf16(af[m], bfr[n], acc[m][n], 0, 0, 0);
    __syncthreads();
  }

  float bv[4];
#pragma unroll
  for (int n = 0; n < 4; ++n) bv[n] = bias[n0 + wc * 64 + n * 16 + l15];
  uint* tl = (uint*)lds;
#pragma unroll
  for (int m = 0; m < 4; ++m) {
    int tro2 = (wr * 64 + m * 16 + l4 * 4) >> 1;
#pragma unroll
    for (int n = 0; n < 4; ++n) {
      int col = wc * 64 + n * 16 + l15;
      uint v0 = (uint)f2bf(acc[m][n][0] + bv[n]) | ((uint)f2bf(acc[m][n][1] + bv[n]) << 16);
      uint v1 = (uint)f2bf(acc[m][n][2] + bv[n]) | ((uint)f2bf(acc[m][n][3] + bv[n]) << 16);
      tl[col * 68 + tro2] = v0;
      tl[col * 68 + tro2 + 1] = v1;
    }
  }
  __syncthreads();
  const int scol = tid >> 1, shalf = tid & 1;
  const int bb = m0 >> 10, t0 = (m0 & 1023) + shalf * 64;
  ushort* g = xw + ((uint)((dir * 64 + bb) * 1024 + (n0 + scol))) * 1024u + t0;
  const uint* s = tl + scol * 68 + shalf * 32;
#pragma unroll
  for (int j = 0; j < 8; ++j)
    *(uint4*)(g + j * 8) = *(const uint4*)(s + j * 4);
}

// ================= recurrence: 16 persistent blocks =================
// bid: half = bid>>3 (partner = bid^8), dir = (bid>>2)&1, grp = bid&3
// Cross-block exchange: RELAXED agent-scope (sc1, no cache flush) atomics,
// per-wave flags, manual s_waitcnt ordering. One raw s_barrier per step.
__global__ __launch_bounds__(512, 2) void k_rec(
    const ushort* __restrict__ xw, const ushort* __restrict__ ut,
    const float* __restrict__ pif, const float* __restrict__ pff, const float* __restrict__ pof,
    const float* __restrict__ pib, const float* __restrict__ pfb, const float* __restrict__ pob,
    ushort* hbuf, uint* flags, float* __restrict__ out)
{
  const int bid = blockIdx.x;
  const int half = bid >> 3;
  const int dir = (bid >> 2) & 1;
  const int grp = bid & 3;
  const int tid = threadIdx.x;
  const int lane = tid & 63, wave = tid >> 6;
  const int l15 = lane & 15, l4 = lane >> 4;
  const int u_loc = wave * 16 + l15;         // 0..127
  const int u_glb = half * 128 + u_loc;      // 0..255
  const int bg = grp * 16;

  const float* piP = dir ? pib : pif;
  const float* pfP = dir ? pfb : pff;
  const float* poP = dir ? pob : pof;
  const float ppi = piP[u_glb], ppf = pfP[u_glb], ppo = poP[u_glb];

  // U fragments, statically indexed: bown = this block's k-half, both = partner's k-half
  bf16x8 bown[4][4], both[4][4];
  const ushort* U = ut + dir * 262144;
#pragma unroll
  for (int nt = 0; nt < 4; ++nt) {
    const ushort* up = U + (nt * 256 + u_glb) * 256;
#pragma unroll
    for (int j = 0; j < 4; ++j) {
      bown[j][nt] = *(const bf16x8*)(up + (half * 4 + j) * 32 + l4 * 8);
      both[j][nt] = *(const bf16x8*)(up + ((half ^ 1) * 4 + j) * 32 + l4 * 8);
    }
  }

  __shared__ __align__(16) ushort hst[2][16][136];   // [parity][batch][own 128 u + pad]
  for (int i = tid; i < 2 * 16 * 136; i += 512) ((ushort*)hst)[i] = 0;

  uint* flags_own = flags + (dir * 4 + grp) * 16 + half * 8;
  uint* flags_par = flags + (dir * 4 + grp) * 16 + (half ^ 1) * 8;
#define HBB(p, hf) (hbuf + (((((p)*2 + dir) * 4 + grp) * 2 + (hf)) * 2048))

  const ushort* xp = xw + ((uint)((dir * 64 + bg + l4 * 4) * 1024 + u_glb)) * 1024u;
  float* outp = out + ((uint)(bg + l4 * 4) * 1024u) * 512u + dir * 256 + u_glb;

  float cr[4] = {0.f, 0.f, 0.f, 0.f};
  __syncthreads();

  for (int t4 = 0; t4 < 1024; t4 += 4) {
    const int tload = dir ? (1020 - t4) : t4;
    uint2 xwb[4][4];
#pragma unroll
    for (int nt = 0; nt < 4; ++nt)
#pragma unroll
      for (int r = 0; r < 4; ++r)
        xwb[nt][r] = *(const uint2*)(xp + (uint)r * 1048576u + (uint)nt * 262144u + tload);

#pragma unroll
    for (int ph = 0; ph < 4; ++ph) {
      const int t = t4 + ph;
      const int rp = (t + 1) & 1;     // parity holding h_{t-1}
      const int wp = t & 1;

      // ---- A/B: poll partner flags, load partner A-fragments (sc1, L1/L2-bypass)
      bf16x8 pfrag[4] = {};
      if (t > 0) {
        uint fv;
        do {
          fv = __hip_atomic_load(flags_par + (lane & 7), __ATOMIC_RELAXED, __HIP_MEMORY_SCOPE_AGENT);
        } while (__ballot(fv < (uint)t) != 0ull);
        const u64* src = (const u64*)HBB(rp, half ^ 1);
        const int bo = l15 * 32 + l4 * 2;
#pragma unroll
        for (int j = 0; j < 4; ++j) {
          u64 lo = __hip_atomic_load(src + bo + j * 8, __ATOMIC_RELAXED, __HIP_MEMORY_SCOPE_AGENT);
          u64 hi = __hip_atomic_load(src + bo + j * 8 + 1, __ATOMIC_RELAXED, __HIP_MEMORY_SCOPE_AGENT);
          union { u64 q[2]; bf16x8 v; } qq;
          qq.q[0] = lo; qq.q[1] = hi;
          pfrag[j] = qq.v;
        }
      }

      // ---- C/D: own-half MFMAs first (LDS), partner-half after (covers sc1 latency)
      f32x4 acc0 = {0.f, 0.f, 0.f, 0.f}, acc1 = acc0, acc2 = acc0, acc3 = acc0;
#pragma unroll
      for (int j = 0; j < 4; ++j) {
        bf16x8 a = *(const bf16x8*)&hst[rp][l15][j * 32 + l4 * 8];
        acc0 = __builtin_amdgcn_mfma_f32_16x16x32_bf16(a, bown[j][0], acc0, 0, 0, 0);
        acc1 = __builtin_amdgcn_mfma_f32_16x16x32_bf16(a, bown[j][1], acc1, 0, 0, 0);
        acc2 = __builtin_amdgcn_mfma_f32_16x16x32_bf16(a, bown[j][2], acc2, 0, 0, 0);
        acc3 = __builtin_amdgcn_mfma_f32_16x16x32_bf16(a, bown[j][3], acc3, 0, 0, 0);
      }
#pragma unroll
      for (int j = 0; j < 4; ++j) {
        bf16x8 a = pfrag[j];
        acc0 = __builtin_amdgcn_mfma_f32_16x16x32_bf16(a, both[j][0], acc0, 0, 0, 0);
        acc1 = __builtin_amdgcn_mfma_f32_16x16x32_bf16(a, both[j][1], acc1, 0, 0, 0);
        acc2 = __builtin_amdgcn_mfma_f32_16x16x32_bf16(a, both[j][2], acc2, 0, 0, 0);
        acc3 = __builtin_amdgcn_mfma_f32_16x16x32_bf16(a, both[j][3], acc3, 0, 0, 0);
      }

      // ---- G/H/I: elementwise; store h to hbuf (sc1) early, LDS, keep for out
      const int phe = dir ? (3 - ph) : ph;
      const int tout = dir ? (1023 - t) : t;
      ushort* dstb = HBB(wp, half);
      float hv[4];
#pragma unroll
      for (int r = 0; r < 4; ++r) {
        float cc = cr[r];
        float gi = acc0[r] + bfsel(xwb[0][r], phe);
        float gf = acc1[r] + bfsel(xwb[1][r], phe);
        float gg = acc2[r] + bfsel(xwb[2][r], phe);
        float go = acc3[r] + bfsel(xwb[3][r], phe);
        float iv = fsig(gi + ppi * cc);
        float fv2 = fsig(gf + ppf * cc);
        float cn = fv2 * cc + iv * ftanh(gg);
        float ov = fsig(go + ppo * cn);
        float h = ov * ftanh(cn);
        cr[r] = cn;
        hv[r] = h;
        ushort hb = f2bf(h);
        __hip_atomic_store(dstb + (l4 * 4 + r) * 128 + u_loc, hb,
                           __ATOMIC_RELAXED, __HIP_MEMORY_SCOPE_AGENT);
        hst[wp][l4 * 4 + r][u_loc] = hb;
      }

      // ---- J: drain hbuf stores to coherence point, then release per-wave flag
      asm volatile("s_waitcnt vmcnt(0)" ::: "memory");
      if (lane == 0)
        __hip_atomic_store(flags_own + wave, (uint)(t + 1),
                           __ATOMIC_RELAXED, __HIP_MEMORY_SCOPE_AGENT);

      // ---- K: out stores (nontemporal), off the cross-block critical path
#pragma unroll
      for (int r = 0; r < 4; ++r)
        __builtin_nontemporal_store(hv[r], outp + (uint)r * 524288u + (uint)tout * 512u);

      // ---- L: LDS visibility + intra-block barrier (no vmcnt drain here)
      asm volatile("s_waitcnt lgkmcnt(0)\n\ts_barrier" ::: "memory");
    }
  }
#undef HBB
}

// ================= dropout (exact JAX threefry) =================
#define TFR(r) { x0 += x1; x1 = (x1 << (r)) | (x1 >> (32 - (r))); x1 ^= x0; }
#define RND4A TFR(13) TFR(15) TFR(26) TFR(6)
#define RND4B TFR(17) TFR(29) TFR(16) TFR(24)

static __device__ __forceinline__ void threefry(uint c0, uint c1, uint& y0, uint& y1) {
  const uint k0 = 0u, k1 = 42u;
  const uint ks2 = k0 ^ k1 ^ 0x1BD11BDAu;
  uint x0 = c0 + k0, x1 = c1 + k1;
  RND4A x0 += k1;  x1 += ks2 + 1u;
  RND4B x0 += ks2; x1 += k0 + 2u;
  RND4A x0 += k0;  x1 += k1 + 3u;
  RND4B x0 += k1;  x1 += ks2 + 4u;
  RND4A x0 += ks2; x1 += k0 + 5u;
  y0 = x0; y1 = x1;
}

__global__ __launch_bounds__(256) void k_drop(float* out, uint n) {
  uint i = blockIdx.x * 256u + threadIdx.x;
  if (i < n) {
    uint y0, y1;
    threefry(0u, i, y0, y1);
    uint w = y0 ^ y1;
    float v = out[i];
    out[i] = (w >> 31) ? 0.0f : v * 2.0f;
  }
}

// ================= host =================
extern "C" void kernel_launch(void* const* d_in, const int* in_sizes, int n_in,
                              void* d_out, int out_size, void* d_ws, size_t ws_size,
                              hipStream_t stream)
{
  const float* x   = (const float*)d_in[0];
  const float* Wf  = (const float*)d_in[1];
  const float* Uf  = (const float*)d_in[2];
  const float* bf_ = (const float*)d_in[3];
  const float* pif = (const float*)d_in[4];
  const float* pff = (const float*)d_in[5];
  const float* pof = (const float*)d_in[6];
  const float* Wb  = (const float*)d_in[7];
  const float* Ub  = (const float*)d_in[8];
  const float* bb_ = (const float*)d_in[9];
  const float* pib = (const float*)d_in[10];
  const float* pfb = (const float*)d_in[11];
  const float* pob = (const float*)d_in[12];
  float* out = (float*)d_out;
  char* ws = (char*)d_ws;

  if (ws_size < WS_NEED) {
    hipMemsetAsync(d_out, 0, (size_t)out_size * 4, stream);
    return;
  }

  ushort* xwp = (ushort*)(ws + XW_OFF);
  ushort* xbp = (ushort*)(ws + XB_OFF);
  ushort* wtp = (ushort*)(ws + WT_OFF);
  ushort* utp = (ushort*)(ws + UT_OFF);
  ushort* hbuf = (ushort*)(ws + HB_OFF);
  uint* flags = (uint*)(ws + FL_OFF);

  hipMemsetAsync(flags, 0, 512, stream);
  k_convert<<<12288, 256, 0, stream>>>(x, Wf, Wb, Uf, Ub, xbp, wtp, utp);
  k_gemm<<<dim3(512, 8, 2), 256, 0, stream>>>(xbp, wtp, bf_, bb_, xwp);
  k_rec<<<16, 512, 0, stream>>>(xwp, utp, pif, pff, pof, pib, pfb, pob, hbuf, flags, out);
  k_drop<<<(out_size + 255) / 256, 256, 0, stream>>>(out, (uint)out_size);
}

// Round 3
// 5789.724 us; speedup vs baseline: 1.0284x; 1.0284x over previous
//
#include <hip/hip_runtime.h>

typedef unsigned int uint;
typedef unsigned short ushort;
typedef unsigned long long u64;
typedef short bf16x8 __attribute__((ext_vector_type(8)));
typedef float f32x4 __attribute__((ext_vector_type(4)));

// ---------------- workspace layout (bytes) ----------------
#define XW_OFF   0ull                        // ushort [2][64][1024][1024]  (dir,b,col,t) bf16
#define XB_OFF   (XW_OFF + 268435456ull)     // ushort [64*1024*256] x in bf16
#define WT_OFF   (XB_OFF + 33554432ull)      // ushort [2][1024][256]  W^T bf16
#define UT_OFF   (WT_OFF + 1048576ull)       // ushort [2][1024][256]  U^T bf16
#define HB_OFF   (UT_OFF + 1048576ull)       // u64 [2 par][2 dir][4 grp][2 half][16 b][32 uquad]
#define FL_OFF   (HB_OFF + 131072ull)        // uint flags[2 dir][4 grp][2 half][8 wave]
#define WS_NEED  (FL_OFF + 1024ull)

static __device__ __forceinline__ ushort f2bf(float f) {
  uint u = __float_as_uint(f);
  return (ushort)((u + 0x7fffu + ((u >> 16) & 1u)) >> 16);
}
static __device__ __forceinline__ float fsig(float x) {
  return 1.0f / (1.0f + __expf(-x));
}
static __device__ __forceinline__ float ftanh(float x) {
  return 1.0f - 2.0f / (__expf(2.0f * x) + 1.0f);
}
static __device__ __forceinline__ float bfsel(uint2 v, int p) {
  uint w = (p & 2) ? v.y : v.x;
  uint bits = (p & 1) ? (w & 0xffff0000u) : (w << 16);
  return __uint_as_float(bits);
}

// ================= convert: x->bf16, W^T, U^T =================
__global__ __launch_bounds__(256) void k_convert(
    const float* __restrict__ x,
    const float* __restrict__ Wf, const float* __restrict__ Wb,
    const float* __restrict__ Uf, const float* __restrict__ Ub,
    ushort* __restrict__ xb, ushort* __restrict__ wt, ushort* __restrict__ ut)
{
  uint tid = blockIdx.x * 256u + threadIdx.x;
  if (tid < 2097152u) {
    uint base = tid * 8u;
    float4 a = *(const float4*)(x + base);
    float4 b = *(const float4*)(x + base + 4);
    uint4 o;
    o.x = (uint)f2bf(a.x) | ((uint)f2bf(a.y) << 16);
    o.y = (uint)f2bf(a.z) | ((uint)f2bf(a.w) << 16);
    o.z = (uint)f2bf(b.x) | ((uint)f2bf(b.y) << 16);
    o.w = (uint)f2bf(b.z) | ((uint)f2bf(b.w) << 16);
    *(uint4*)(xb + base) = o;
  } else {
    uint e = tid - 2097152u;
    uint which = e >> 18;
    uint i = e & 262143u;
    uint n = i >> 8, k = i & 255u;
    const float* src = (which == 0) ? Wf : (which == 1) ? Wb : (which == 2) ? Uf : Ub;
    ushort v = f2bf(src[k * 1024u + n]);
    ushort* dst = (which < 2) ? (wt + which * 262144u) : (ut + (which - 2u) * 262144u);
    dst[n * 256u + k] = v;
  }
}

// ================= GEMM: xw[dir][b][col][t] = x @ W + bias =================
__global__ __launch_bounds__(256) void k_gemm(
    const ushort* __restrict__ xb, const ushort* __restrict__ wt,
    const float* __restrict__ biasF, const float* __restrict__ biasB,
    ushort* __restrict__ xw)
{
  const int dir = blockIdx.z;
  const ushort* W = wt + dir * 262144;
  const float* bias = dir ? biasB : biasF;
  const int m0 = blockIdx.x * 128;
  const int n0 = blockIdx.y * 128;
  const int tid = threadIdx.x;
  const int lane = tid & 63, wave = tid >> 6;
  const int l15 = lane & 15, l4 = lane >> 4;
  const int wr = wave >> 1, wc = wave & 1;

  __shared__ __align__(16) ushort lds[17408];
  ushort* As = lds;
  ushort* Bs = lds + 5120;

  f32x4 acc[4][4] = {};
  const int arow = tid >> 1, aseg = tid & 1;

  for (int kit = 0; kit < 8; ++kit) {
    int k0 = kit * 32;
    const ushort* sa = xb + (m0 + arow) * 256 + k0 + aseg * 16;
    uint4 a0 = *(const uint4*)sa;
    uint4 a1 = *(const uint4*)(sa + 8);
    const ushort* sb = W + (n0 + arow) * 256 + k0 + aseg * 16;
    uint4 b0 = *(const uint4*)sb;
    uint4 b1 = *(const uint4*)(sb + 8);
    *(uint4*)(As + arow * 40 + aseg * 16) = a0;
    *(uint4*)(As + arow * 40 + aseg * 16 + 8) = a1;
    *(uint4*)(Bs + arow * 40 + aseg * 16) = b0;
    *(uint4*)(Bs + arow * 40 + aseg * 16 + 8) = b1;
    __syncthreads();
    bf16x8 af[4], bfr[4];
#pragma unroll
    for (int m = 0; m < 4; ++m) af[m] = *(const bf16x8*)(As + (wr * 64 + m * 16 + l15) * 40 + l4 * 8);
#pragma unroll
    for (int n = 0; n < 4; ++n) bfr[n] = *(const bf16x8*)(Bs + (wc * 64 + n * 16 + l15) * 40 + l4 * 8);
#pragma unroll
    for (int m = 0; m < 4; ++m)
#pragma unroll
      for (int n = 0; n < 4; ++n)
        acc[m][n] = __builtin_amdgcn_mfma_f32_16x16x32_bf16(af[m], bfr[n], acc[m][n], 0, 0, 0);
    __syncthreads();
  }

  float bv[4];
#pragma unroll
  for (int n = 0; n < 4; ++n) bv[n] = bias[n0 + wc * 64 + n * 16 + l15];
  uint* tl = (uint*)lds;
#pragma unroll
  for (int m = 0; m < 4; ++m) {
    int tro2 = (wr * 64 + m * 16 + l4 * 4) >> 1;
#pragma unroll
    for (int n = 0; n < 4; ++n) {
      int col = wc * 64 + n * 16 + l15;
      uint v0 = (uint)f2bf(acc[m][n][0] + bv[n]) | ((uint)f2bf(acc[m][n][1] + bv[n]) << 16);
      uint v1 = (uint)f2bf(acc[m][n][2] + bv[n]) | ((uint)f2bf(acc[m][n][3] + bv[n]) << 16);
      tl[col * 68 + tro2] = v0;
      tl[col * 68 + tro2 + 1] = v1;
    }
  }
  __syncthreads();
  const int scol = tid >> 1, shalf = tid & 1;
  const int bb = m0 >> 10, t0 = (m0 & 1023) + shalf * 64;
  ushort* g = xw + ((uint)((dir * 64 + bb) * 1024 + (n0 + scol))) * 1024u + t0;
  const uint* s = tl + scol * 68 + shalf * 32;
#pragma unroll
  for (int j = 0; j < 8; ++j)
    *(uint4*)(g + j * 8) = *(const uint4*)(s + j * 4);
}

// ================= recurrence: 16 persistent blocks =================
// bid: half = bid>>3 (partner = bid^8), dir = (bid>>2)&1, grp = bid&3
// Per-step: own MFMAs (flag poll in flight) -> partner dwordx4 loads (sc0 sc1)
// -> partner MFMAs -> elementwise -> LDS ring write -> barrier -> LDS->global
// u64 copy-out -> per-wave vmcnt(0) -> per-wave flag -> deferred out flush.
__global__ __launch_bounds__(512, 2) void k_rec(
    const ushort* __restrict__ xw, const ushort* __restrict__ ut,
    const float* __restrict__ pif, const float* __restrict__ pff, const float* __restrict__ pof,
    const float* __restrict__ pib, const float* __restrict__ pfb, const float* __restrict__ pob,
    u64* hbuf, uint* flags, float* __restrict__ out)
{
  const int bid = blockIdx.x;
  const int half = bid >> 3;
  const int dir = (bid >> 2) & 1;
  const int grp = bid & 3;
  const int tid = threadIdx.x;
  const int lane = tid & 63, wave = tid >> 6;
  const int l15 = lane & 15, l4 = lane >> 4;
  const int u_loc = wave * 16 + l15;         // 0..127
  const int u_glb = half * 128 + u_loc;      // 0..255
  const int bg = grp * 16;

  const float* piP = dir ? pib : pif;
  const float* pfP = dir ? pfb : pff;
  const float* poP = dir ? pob : pof;
  const float ppi = piP[u_glb], ppf = pfP[u_glb], ppo = poP[u_glb];

  // U fragments: bown = this block's k-half, both = partner's k-half
  bf16x8 bown[4][4], both[4][4];
  const ushort* U = ut + dir * 262144;
#pragma unroll
  for (int nt = 0; nt < 4; ++nt) {
    const ushort* up = U + (nt * 256 + u_glb) * 256;
#pragma unroll
    for (int j = 0; j < 4; ++j) {
      bown[j][nt] = *(const bf16x8*)(up + (half * 4 + j) * 32 + l4 * 8);
      both[j][nt] = *(const bf16x8*)(up + ((half ^ 1) * 4 + j) * 32 + l4 * 8);
    }
  }

  // 16-slot h ring: [slot][b(16)][136 u]  (b-stride 272B = 17*16 -> b128 conflict-free)
  __shared__ __align__(16) ushort stg[16 * 16 * 136];
  for (int i = tid; i < 16 * 16 * 136; i += 512) stg[i] = 0;

  uint* flags_own = flags + (dir * 4 + grp) * 16 + half * 8;
  uint* flags_par = flags + (dir * 4 + grp) * 16 + (half ^ 1) * 8;
#define HTILE(p, hf) (hbuf + ((((p)*2 + dir) * 4 + grp) * 2 + (hf)) * 512)

  const ushort* xp = xw + ((uint)((dir * 64 + bg + l4 * 4) * 1024 + u_glb)) * 1024u;

  // copy-out / flush mapping: thread -> (cb batch-row, cq u-quad)
  const int cb = tid >> 5, cq = tid & 31;
  float* outbase = out + ((uint)(bg + cb) * 1024u) * 512u + dir * 256 + half * 128 + cq * 4;

  float cr[4] = {0.f, 0.f, 0.f, 0.f};
  __syncthreads();

  for (int t4 = 0; t4 < 1024; t4 += 4) {
    const int tload = dir ? (1020 - t4) : t4;
    uint2 xwb[4][4];
#pragma unroll
    for (int nt = 0; nt < 4; ++nt)
#pragma unroll
      for (int r = 0; r < 4; ++r)
        xwb[nt][r] = *(const uint2*)(xp + (uint)r * 1048576u + (uint)nt * 262144u + tload);

#pragma unroll
    for (int ph = 0; ph < 4; ++ph) {
      const int t = t4 + ph;

      // ---- early flag sample (load flies under own MFMAs)
      uint fv0 = 0xFFFFFFFFu;
      if (t > 0)
        fv0 = __hip_atomic_load(flags_par + (lane & 7), __ATOMIC_RELAXED, __HIP_MEMORY_SCOPE_AGENT);

      // ---- own-half MFMAs from ring slot (t-1)&15
      const ushort* sA = stg + ((t - 1) & 15) * 2176;
      f32x4 acc0 = {0.f, 0.f, 0.f, 0.f}, acc1 = acc0, acc2 = acc0, acc3 = acc0;
#pragma unroll
      for (int j = 0; j < 4; ++j) {
        bf16x8 a = *(const bf16x8*)(sA + l15 * 136 + j * 32 + l4 * 8);
        acc0 = __builtin_amdgcn_mfma_f32_16x16x32_bf16(a, bown[j][0], acc0, 0, 0, 0);
        acc1 = __builtin_amdgcn_mfma_f32_16x16x32_bf16(a, bown[j][1], acc1, 0, 0, 0);
        acc2 = __builtin_amdgcn_mfma_f32_16x16x32_bf16(a, bown[j][2], acc2, 0, 0, 0);
        acc3 = __builtin_amdgcn_mfma_f32_16x16x32_bf16(a, bown[j][3], acc3, 0, 0, 0);
      }

      // ---- partner half
      if (t > 0) {
        if (__ballot(fv0 < (uint)t) != 0ull) {
          uint fv;
          do {
            fv = __hip_atomic_load(flags_par + (lane & 7), __ATOMIC_RELAXED, __HIP_MEMORY_SCOPE_AGENT);
          } while (__ballot(fv < (uint)t) != 0ull);
        }
        const u64* pb = HTILE((t + 1) & 1, half ^ 1) + l15 * 32 + l4 * 2;
        uint4 q0, q1, q2, q3;
        asm volatile(
            "global_load_dwordx4 %0, %4, off sc0 sc1\n\t"
            "global_load_dwordx4 %1, %5, off sc0 sc1\n\t"
            "global_load_dwordx4 %2, %6, off sc0 sc1\n\t"
            "global_load_dwordx4 %3, %7, off sc0 sc1\n\t"
            "s_waitcnt vmcnt(0)"
            : "=&v"(q0), "=&v"(q1), "=&v"(q2), "=&v"(q3)
            : "v"(pb), "v"(pb + 8), "v"(pb + 16), "v"(pb + 24)
            : "memory");
        union { uint4 u; bf16x8 v; } c0, c1, c2, c3;
        c0.u = q0; c1.u = q1; c2.u = q2; c3.u = q3;
        acc0 = __builtin_amdgcn_mfma_f32_16x16x32_bf16(c0.v, both[0][0], acc0, 0, 0, 0);
        acc1 = __builtin_amdgcn_mfma_f32_16x16x32_bf16(c0.v, both[0][1], acc1, 0, 0, 0);
        acc2 = __builtin_amdgcn_mfma_f32_16x16x32_bf16(c0.v, both[0][2], acc2, 0, 0, 0);
        acc3 = __builtin_amdgcn_mfma_f32_16x16x32_bf16(c0.v, both[0][3], acc3, 0, 0, 0);
        acc0 = __builtin_amdgcn_mfma_f32_16x16x32_bf16(c1.v, both[1][0], acc0, 0, 0, 0);
        acc1 = __builtin_amdgcn_mfma_f32_16x16x32_bf16(c1.v, both[1][1], acc1, 0, 0, 0);
        acc2 = __builtin_amdgcn_mfma_f32_16x16x32_bf16(c1.v, both[1][2], acc2, 0, 0, 0);
        acc3 = __builtin_amdgcn_mfma_f32_16x16x32_bf16(c1.v, both[1][3], acc3, 0, 0, 0);
        acc0 = __builtin_amdgcn_mfma_f32_16x16x32_bf16(c2.v, both[2][0], acc0, 0, 0, 0);
        acc1 = __builtin_amdgcn_mfma_f32_16x16x32_bf16(c2.v, both[2][1], acc1, 0, 0, 0);
        acc2 = __builtin_amdgcn_mfma_f32_16x16x32_bf16(c2.v, both[2][2], acc2, 0, 0, 0);
        acc3 = __builtin_amdgcn_mfma_f32_16x16x32_bf16(c2.v, both[2][3], acc3, 0, 0, 0);
        acc0 = __builtin_amdgcn_mfma_f32_16x16x32_bf16(c3.v, both[3][0], acc0, 0, 0, 0);
        acc1 = __builtin_amdgcn_mfma_f32_16x16x32_bf16(c3.v, both[3][1], acc1, 0, 0, 0);
        acc2 = __builtin_amdgcn_mfma_f32_16x16x32_bf16(c3.v, both[3][2], acc2, 0, 0, 0);
        acc3 = __builtin_amdgcn_mfma_f32_16x16x32_bf16(c3.v, both[3][3], acc3, 0, 0, 0);
      }

      // ---- elementwise; write h to ring slot t&15 (LDS only)
      const int phe = dir ? (3 - ph) : ph;
      ushort* sW = stg + (t & 15) * 2176;
#pragma unroll
      for (int r = 0; r < 4; ++r) {
        float cc = cr[r];
        float gi = acc0[r] + bfsel(xwb[0][r], phe);
        float gf = acc1[r] + bfsel(xwb[1][r], phe);
        float gg = acc2[r] + bfsel(xwb[2][r], phe);
        float go = acc3[r] + bfsel(xwb[3][r], phe);
        float iv = fsig(gi + ppi * cc);
        float fv2 = fsig(gf + ppf * cc);
        float cn = fv2 * cc + iv * ftanh(gg);
        float ov = fsig(go + ppo * cn);
        float h = ov * ftanh(cn);
        cr[r] = cn;
        sW[(l4 * 4 + r) * 136 + u_loc] = f2bf(h);
      }

      // ---- barrier (LDS visibility only; no vmcnt drain)
      asm volatile("s_waitcnt lgkmcnt(0)\n\ts_barrier" ::: "memory");

      // ---- copy-out own tile LDS->global (u64, [b][uquad]), drain, flag
      {
        u64 v = *(const u64*)(sW + cb * 136 + cq * 4);
        u64* dst = HTILE(t & 1, half) + cb * 32 + cq;
        asm volatile("global_store_dwordx2 %0, %1, off sc0 sc1" :: "v"(dst), "v"(v) : "memory");
        asm volatile("s_waitcnt vmcnt(0)" ::: "memory");
      }
      if (lane == 0)
        __hip_atomic_store(flags_own + wave, (uint)(t + 1),
                           __ATOMIC_RELAXED, __HIP_MEMORY_SCOPE_AGENT);

      // ---- deferred out flush: slice t-8 (off the cross-block critical path)
      if (t >= 8) {
        const int ts = t - 8;
        u64 hv4 = *(const u64*)(stg + (ts & 15) * 2176 + cb * 136 + cq * 4);
        float4 o;
        o.x = __uint_as_float(((uint)hv4 & 0xffffu) << 16);
        o.y = __uint_as_float((uint)hv4 & 0xffff0000u);
        o.z = __uint_as_float(((uint)(hv4 >> 32) & 0xffffu) << 16);
        o.w = __uint_as_float((uint)(hv4 >> 32) & 0xffff0000u);
        const int tout = dir ? (1023 - ts) : ts;
        *(float4*)(outbase + (uint)tout * 512u) = o;
      }
    }
  }

  // ---- tail flush: slices 1016..1023
#pragma unroll
  for (int ts = 1016; ts < 1024; ++ts) {
    u64 hv4 = *(const u64*)(stg + (ts & 15) * 2176 + cb * 136 + cq * 4);
    float4 o;
    o.x = __uint_as_float(((uint)hv4 & 0xffffu) << 16);
    o.y = __uint_as_float((uint)hv4 & 0xffff0000u);
    o.z = __uint_as_float(((uint)(hv4 >> 32) & 0xffffu) << 16);
    o.w = __uint_as_float((uint)(hv4 >> 32) & 0xffff0000u);
    const int tout = dir ? (1023 - ts) : ts;
    *(float4*)(outbase + (uint)tout * 512u) = o;
  }
#undef HTILE
}

// ================= dropout (exact JAX threefry, in-place on out) =================
#define TFR(r) { x0 += x1; x1 = (x1 << (r)) | (x1 >> (32 - (r))); x1 ^= x0; }
#define RND4A TFR(13) TFR(15) TFR(26) TFR(6)
#define RND4B TFR(17) TFR(29) TFR(16) TFR(24)

static __device__ __forceinline__ void threefry(uint c0, uint c1, uint& y0, uint& y1) {
  const uint k0 = 0u, k1 = 42u;
  const uint ks2 = k0 ^ k1 ^ 0x1BD11BDAu;
  uint x0 = c0 + k0, x1 = c1 + k1;
  RND4A x0 += k1;  x1 += ks2 + 1u;
  RND4B x0 += ks2; x1 += k0 + 2u;
  RND4A x0 += k0;  x1 += k1 + 3u;
  RND4B x0 += k1;  x1 += ks2 + 4u;
  RND4A x0 += ks2; x1 += k0 + 5u;
  y0 = x0; y1 = x1;
}

__global__ __launch_bounds__(256) void k_drop(float* out, uint n) {
  uint i = blockIdx.x * 256u + threadIdx.x;
  if (i < n) {
    uint y0, y1;
    threefry(0u, i, y0, y1);
    uint w = y0 ^ y1;
    float v = out[i];
    out[i] = (w >> 31) ? 0.0f : v * 2.0f;
  }
}

// ================= host =================
extern "C" void kernel_launch(void* const* d_in, const int* in_sizes, int n_in,
                              void* d_out, int out_size, void* d_ws, size_t ws_size,
                              hipStream_t stream)
{
  const float* x   = (const float*)d_in[0];
  const float* Wf  = (const float*)d_in[1];
  const float* Uf  = (const float*)d_in[2];
  const float* bf_ = (const float*)d_in[3];
  const float* pif = (const float*)d_in[4];
  const float* pff = (const float*)d_in[5];
  const float* pof = (const float*)d_in[6];
  const float* Wb  = (const float*)d_in[7];
  const float* Ub  = (const float*)d_in[8];
  const float* bb_ = (const float*)d_in[9];
  const float* pib = (const float*)d_in[10];
  const float* pfb = (const float*)d_in[11];
  const float* pob = (const float*)d_in[12];
  float* out = (float*)d_out;
  char* ws = (char*)d_ws;

  if (ws_size < WS_NEED) {
    hipMemsetAsync(d_out, 0, (size_t)out_size * 4, stream);
    return;
  }

  ushort* xwp = (ushort*)(ws + XW_OFF);
  ushort* xbp = (ushort*)(ws + XB_OFF);
  ushort* wtp = (ushort*)(ws + WT_OFF);
  ushort* utp = (ushort*)(ws + UT_OFF);
  u64* hbuf   = (u64*)(ws + HB_OFF);
  uint* flags = (uint*)(ws + FL_OFF);

  hipMemsetAsync(flags, 0, 512, stream);
  k_convert<<<12288, 256, 0, stream>>>(x, Wf, Wb, Uf, Ub, xbp, wtp, utp);
  k_gemm<<<dim3(512, 8, 2), 256, 0, stream>>>(xbp, wtp, bf_, bb_, xwp);
  k_rec<<<16, 512, 0, stream>>>(xwp, utp, pif, pff, pof, pib, pfb, pob, hbuf, flags, out);
  k_drop<<<(out_size + 255) / 256, 256, 0, stream>>>(out, (uint)out_size);
}